// Round 10
// baseline (490.764 us; speedup 1.0000x reference)
//
#include <hip/hip_runtime.h>
#include <hip/hip_bf16.h>

#define N_NODES    100000
#define N_EDGES    1200000
#define NUM_GRAPHS 128
#define IN_DIM     5
#define HIDDEN     64
#define M_TILES    (N_NODES / 16)   // 6250 (exact; 6250*16 == N_NODES)
#define NI4        (N_EDGES / 4)    // 300000 int4 groups

#define CB    782                   // coarse buckets of 128 nodes: ceil(N/128)
#define CBLK  256                   // partition blocks
#define EPB   ((NI4 + CBLK - 1) / CBLK)   // 1172 int4-groups per block
#define STCAP 3072                  // LDS edge-payload capacity (avg 1534/bucket)
#define AGP   72                    // LDS gathered-tile row stride (halfwords)
#define G2BLKS 2048                 // gather2_mlp2 grid

typedef __attribute__((ext_vector_type(8))) short short8;   // 8 bf16 (4 VGPRs)
typedef __attribute__((ext_vector_type(4))) float f32x4;
typedef __attribute__((ext_vector_type(2))) float f32x2;

#if defined(__has_builtin)
#if __has_builtin(__builtin_amdgcn_cvt_pk_f32_fp8)
#define HAS_HWF8 1
#endif
#endif

// fp32 -> bf16 bits (RNE)
__device__ __forceinline__ unsigned short f2bs(float f) {
    union { float f; unsigned u; } v; v.f = f;
    return (unsigned short)((v.u + 0x7FFFu + ((v.u >> 16) & 1u)) >> 16);
}
// bf16 bits -> fp32
__device__ __forceinline__ float bs2f(unsigned short s) {
    union { unsigned u; float f; } v; v.u = ((unsigned)s) << 16;
    return v.f;
}
__device__ __forceinline__ float blo(unsigned p) { return bs2f((unsigned short)(p & 0xffff)); }
__device__ __forceinline__ float bhi(unsigned p) { return bs2f((unsigned short)(p >> 16)); }
__device__ __forceinline__ unsigned pack2(float a, float b) {
    return ((unsigned)f2bs(b) << 16) | (unsigned)f2bs(a);
}

// fp32 (>=0) -> fp8 e4m3 bits (OCP), RNE, denorm-exact (magic-multiply trick)
__device__ __forceinline__ unsigned char f2f8(float f) {
    union { float f; unsigned u; } v; v.f = f * 0x1p-120f;
    unsigned u = v.u + 0x7FFFFu + ((v.u >> 20) & 1u);
    return (unsigned char)(u >> 20);
}
// fp8 e4m3 bits -> fp32 (exact inverse)
__device__ __forceinline__ float f82f(unsigned b) {
    union { unsigned u; float f; } v; v.u = (b & 0x7Fu) << 20;
    return v.f * 0x1p120f;
}

// accumulate 4 fp8 bytes of r into a (HW decode when available; bit-identical)
__device__ __forceinline__ void acc8(float4& a, unsigned r) {
#ifdef HAS_HWF8
    f32x2 lo = __builtin_amdgcn_cvt_pk_f32_fp8((int)r, false);
    f32x2 hi = __builtin_amdgcn_cvt_pk_f32_fp8((int)r, true);
    a.x += lo[0]; a.y += lo[1]; a.z += hi[0]; a.w += hi[1];
#else
    a.x += f82f(r); a.y += f82f(r >> 8); a.z += f82f(r >> 16); a.w += f82f(r >> 24);
#endif
}

__device__ __forceinline__ int lower_bound_i(const int* a, int n, int v) {
    int lo = 0, hi = n;
    while (lo < hi) { int mid = (lo + hi) >> 1; if (a[mid] < v) lo = mid + 1; else hi = mid; }
    return lo;
}

// ==================== CSR build: two-level counting sort ====================
// part entries are PACKED 4B: src (bits 0..16) | (dst & 127) << 17.
// Ledger: no grid.sync (r6: ~45us each); no per-block column-sum self-scan
// (r7: latency-bound, 65us); dispatch boundaries are cheap (~1-2us, r8).

// ---- Pass A: coarse histogram (dst>>7, LDS) + xb pack + misc init ----------
__global__ void coarse_count(const int* __restrict__ dst, int* __restrict__ gcnt,
                             const float* __restrict__ x, uint4* __restrict__ xb,
                             float* __restrict__ add_pool, int* __restrict__ ptr,
                             int* __restrict__ done_ctr) {
    __shared__ int h[CB];
    int t = threadIdx.x, b = blockIdx.x;
    for (int i = t; i < CB; i += 256) h[i] = 0;
    __syncthreads();
    int i0 = b * EPB, i1 = min(i0 + EPB, NI4);
    for (int i = i0 + t; i < i1; i += 256) {
        int4 d = ((const int4*)dst)[i];
        atomicAdd(&h[d.x >> 7], 1);
        atomicAdd(&h[d.y >> 7], 1);
        atomicAdd(&h[d.z >> 7], 1);
        atomicAdd(&h[d.w >> 7], 1);
    }
    __syncthreads();
    for (int i = t; i < CB; i += 256) gcnt[b * CB + i] = h[i];

    // fold: pack x rows into 16B (5 bf16 + pad) for the layer-1 edge gather
    for (int n = b * 256 + t; n < N_NODES; n += CBLK * 256) {
        const float* xr = x + (size_t)n * IN_DIM;
        uint4 o;
        o.x = pack2(xr[0], xr[1]);
        o.y = pack2(xr[2], xr[3]);
        o.z = pack2(xr[4], 0.0f);
        o.w = 0u;
        xb[n] = o;
    }
    // fold: zero add_pool + completion counter, terminate ptr
    if (b == 0) {
        for (int i = t; i < NUM_GRAPHS * HIDDEN; i += 256) add_pool[i] = 0.0f;
        if (t == 0) { ptr[N_NODES] = N_EDGES; *done_ctr = 0; }
    }
}

// ---- Pass B: per-bucket exclusive scan over the 256 partition blocks -------
__global__ void block_scan(int* __restrict__ gcnt, int* __restrict__ btot) {
    __shared__ int s[CBLK];
    int k = blockIdx.x, t = threadIdx.x;
    int v = gcnt[t * CB + k];
    s[t] = v;
    __syncthreads();
    for (int off = 1; off < CBLK; off <<= 1) {
        int u = (t >= off) ? s[t - off] : 0;
        __syncthreads();
        s[t] += u;
        __syncthreads();
    }
    gcnt[t * CB + k] = s[t] - v;
    if (t == CBLK - 1) btot[k] = s[t];
}

// ---- Pass C: partition; bstart recomputed locally from btot (cheap) --------
__global__ void partition_k(const int* __restrict__ src, const int* __restrict__ dst,
                            const int* __restrict__ gcnt, const int* __restrict__ btot,
                            int* __restrict__ bstart, int* __restrict__ part) {
    __shared__ int sb[CB];    // btot -> exclusive bucket starts
    __shared__ int base[CB];  // this block's write cursors base
    __shared__ int h[CB];     // scatter cursors
    int t = threadIdx.x, b = blockIdx.x;
    for (int i = t; i < CB; i += 256) sb[i] = btot[i];
    __syncthreads();
    if (t < 64) {
        int loc[13];                      // 64*13 = 832 >= CB
        int base_i = t * 13;
        int sum = 0;
#pragma unroll
        for (int j = 0; j < 13; ++j) {
            int idx = base_i + j;
            int c = (idx < CB) ? sb[idx] : 0;
            loc[j] = sum; sum += c;
        }
        int inc = sum;
#pragma unroll
        for (int off = 1; off < 64; off <<= 1) {
            int u = __shfl_up(inc, off, 64);
            if (t >= off) inc += u;
        }
        int excl = inc - sum;
#pragma unroll
        for (int j = 0; j < 13; ++j) {
            int idx = base_i + j;
            if (idx < CB) sb[idx] = excl + loc[j];
        }
    }
    __syncthreads();
    for (int i = t; i < CB; i += 256) {
        int bs = sb[i];
        base[i] = bs + gcnt[b * CB + i];
        h[i] = 0;
        if (b == 0) bstart[i] = bs;     // publish for fine_gather1
    }
    if (b == 0 && t == 0) bstart[CB] = N_EDGES;
    __syncthreads();
    int i0 = b * EPB, i1 = min(i0 + EPB, NI4);
    for (int i = i0 + t; i < i1; i += 256) {
        int4 s4 = ((const int4*)src)[i];
        int4 d4 = ((const int4*)dst)[i];
        int k, r;
        k = d4.x >> 7; r = atomicAdd(&h[k], 1); part[base[k] + r] = s4.x | ((d4.x & 127) << 17);
        k = d4.y >> 7; r = atomicAdd(&h[k], 1); part[base[k] + r] = s4.y | ((d4.y & 127) << 17);
        k = d4.z >> 7; r = atomicAdd(&h[k], 1); part[base[k] + r] = s4.z | ((d4.z & 127) << 17);
        k = d4.w >> 7; r = atomicAdd(&h[k], 1); part[base[k] + r] = s4.w | ((d4.w & 127) << 17);
    }
}

// ---- Pass D FUSED with Layer 1: fine sort + ptr + LDS-staged gather + MLP --
__global__ void fine_gather1(const int* __restrict__ part, const int* __restrict__ bstart,
                             int* __restrict__ ptr, int* __restrict__ esrc,
                             const uint4* __restrict__ xb,
                             const float* __restrict__ x,
                             const float* __restrict__ w_rel1,
                             const float* __restrict__ b_rel1,
                             const float* __restrict__ w_root1,
                             unsigned short* __restrict__ h1,
                             unsigned char* __restrict__ h1f8) {
    __shared__ int fh[128];       // counts -> exclusive offsets (bucket-local)
    __shared__ int fo[128];       // scan workspace
    __shared__ int fr[128];       // scatter cursors
    __shared__ uint4 stage[STCAP];// 48 KB edge payloads in slot order
    int k = blockIdx.x, t = threadIdx.x;
    int e0 = bstart[k], e1 = bstart[k + 1];
    int ne = e1 - e0;
    bool useLds = (ne <= STCAP);
    if (t < 128) { fh[t] = 0; fr[t] = 0; }
    __syncthreads();
    for (int e = e0 + t; e < e1; e += 256)
        atomicAdd(&fh[(part[e] >> 17) & 127], 1);
    __syncthreads();
    int v = (t < 128) ? fh[t] : 0;
    if (t < 128) fo[t] = v;
    __syncthreads();
    for (int off = 1; off < 128; off <<= 1) {
        int u = (t >= off && t < 128) ? fo[t - off] : 0;
        __syncthreads();
        if (t < 128) fo[t] += u;
        __syncthreads();
    }
    if (t < 128) {
        int excl = fo[t] - v;
        int n_t = (k << 7) + t;
        if (n_t < N_NODES) ptr[n_t] = e0 + excl;
        fh[t] = excl;
    }
    __syncthreads();
    for (int e = e0 + t; e < e1; e += 256) {
        int p = part[e];
        int d = (p >> 17) & 127;
        int s = p & 0x1FFFF;
        int r = atomicAdd(&fr[d], 1);
        int slot = fh[d] + r;
        esrc[e0 + slot] = s;
        if (useLds) stage[slot] = xb[s];
    }
    __syncthreads();

    int ql = t & 15;
    int g  = t >> 4;
    float wr[IN_DIM][4], wo[IN_DIM][4], bias[4];
#pragma unroll
    for (int j = 0; j < 4; ++j) {
        int ch = ql * 4 + j;
        bias[j] = b_rel1[ch];
#pragma unroll
        for (int kk = 0; kk < IN_DIM; ++kk) {
            wr[kk][j] = w_rel1[kk * HIDDEN + ch];
            wo[kk][j] = w_root1[kk * HIDDEN + ch];
        }
    }

    for (int nl = g; nl < 128; nl += 16) {
        int n = (k << 7) + nl;
        if (n >= N_NODES) break;
        int s0 = fh[nl];
        int s1 = (nl < 127) ? fh[nl + 1] : ne;
        float a[IN_DIM] = {0.f, 0.f, 0.f, 0.f, 0.f};
        if (useLds) {
            for (int i = s0 + ql; i < s1; i += 16) {
                uint4 p = stage[i];
                a[0] += blo(p.x); a[1] += bhi(p.x);
                a[2] += blo(p.y); a[3] += bhi(p.y);
                a[4] += blo(p.z);
            }
        } else {
            for (int i = s0 + ql; i < s1; i += 16) {
                uint4 p = xb[esrc[e0 + i]];
                a[0] += blo(p.x); a[1] += bhi(p.x);
                a[2] += blo(p.y); a[3] += bhi(p.y);
                a[4] += blo(p.z);
            }
        }
#pragma unroll
        for (int kk = 0; kk < IN_DIM; ++kk) {
            a[kk] += __shfl_xor(a[kk], 1, 64);
            a[kk] += __shfl_xor(a[kk], 2, 64);
            a[kk] += __shfl_xor(a[kk], 4, 64);
            a[kk] += __shfl_xor(a[kk], 8, 64);
        }
        float xr[IN_DIM];
#pragma unroll
        for (int kk = 0; kk < IN_DIM; ++kk) xr[kk] = x[(size_t)n * IN_DIM + kk];

        unsigned short hv[4];
        unsigned char  hf[4];
#pragma unroll
        for (int j = 0; j < 4; ++j) {
            float acc = bias[j];
#pragma unroll
            for (int kk = 0; kk < IN_DIM; ++kk)
                acc += a[kk] * wr[kk][j] + xr[kk] * wo[kk][j];
            float h = fmaxf(acc, 0.0f);
            hv[j] = f2bs(h);
            hf[j] = f2f8(h);
        }
        ushort4 v4; v4.x = hv[0]; v4.y = hv[1]; v4.z = hv[2]; v4.w = hv[3];
        *(ushort4*)(h1 + (size_t)n * HIDDEN + ql * 4) = v4;
        uchar4 c4; c4.x = hf[0]; c4.y = hf[1]; c4.z = hf[2]; c4.w = hf[3];
        *(uchar4*)(h1f8 + (size_t)n * HIDDEN + ql * 4) = c4;
    }
}

// ==================== Layer 2 + head: gather + MFMA + pool + head, FUSED ====
// Per 16-node tile: 16 groups x 16 lanes gather all 16 fp8 rows in parallel,
// pack bf16 into a padded LDS tile, then the 4 waves run the MFMA transform
// + add-pool. After the tile loop, the LAST block to finish (device-scope
// counter, fence-ordered) runs the MLP head for all 128 graphs; add_pool is
// read via atomicAdd(p, 0.0f) so reads are coherent across XCDs.
__global__ void gather2_mlp2(const unsigned* __restrict__ rows,   // fp8 row = 16 dwords
                             const int* __restrict__ ptr,
                             const int* __restrict__ esrc,
                             const unsigned short* __restrict__ h1,
                             const float* __restrict__ w_rel2,
                             const float* __restrict__ b_rel2,
                             const float* __restrict__ w_root2,
                             const int* __restrict__ batch,
                             float* __restrict__ add_pool,
                             int* __restrict__ done_ctr,
                             const float* __restrict__ w_h1,
                             const float* __restrict__ b_h1,
                             const float* __restrict__ w_h2,
                             const float* __restrict__ b_h2,
                             float* __restrict__ out) {
    __shared__ unsigned short ag[16 * AGP];   // gathered tile, bf16, pad 72
    __shared__ int s_last;
    int tid  = threadIdx.x;
    int lane = tid & 63, wv = tid >> 6;
    int row  = lane & 15, quad = lane >> 4;
    int n    = wv * 16 + row;                 // this lane's output column
    int g    = tid >> 4, ql = tid & 15;       // gather roles

    short8 bwr[2], bwo[2];
#pragma unroll
    for (int s = 0; s < 2; ++s)
#pragma unroll
        for (int j = 0; j < 8; ++j) {
            int k = 32 * s + quad * 8 + j;
            bwr[s][j] = (short)f2bs(w_rel2[k * HIDDEN + n]);
            bwo[s][j] = (short)f2bs(w_root2[k * HIDDEN + n]);
        }
    float bias = b_rel2[n];

    for (int t = blockIdx.x; t < M_TILES; t += gridDim.x) {
        int m0 = t * 16;
        // ---- gather phase: group g gathers node m0+g ----
        int nd = m0 + g;
        int start = ptr[nd], end = ptr[nd + 1];
        float4 a0 = {0.f, 0.f, 0.f, 0.f}, a1 = a0;
        int e = start;
        for (; e + 1 < end; e += 2) {
            int sA = esrc[e], sB = esrc[e + 1];
            unsigned r0 = rows[(size_t)sA * 16 + ql];
            unsigned r1 = rows[(size_t)sB * 16 + ql];
            acc8(a0, r0); acc8(a1, r1);
        }
        if (e < end) {
            unsigned r0 = rows[(size_t)esrc[e] * 16 + ql];
            acc8(a0, r0);
        }
        a0.x += a1.x; a0.y += a1.y; a0.z += a1.z; a0.w += a1.w;
        uint2 pk;
        pk.x = pack2(a0.x, a0.y);
        pk.y = pack2(a0.z, a0.w);
        *(uint2*)&ag[g * AGP + ql * 4] = pk;
        __syncthreads();

        // ---- MFMA transform + pool (all 4 waves, same tile) ----
        size_t rbase = (size_t)(m0 + row) * HIDDEN;
        short8 aa0 = *(const short8*)&ag[row * AGP + quad * 8];
        short8 aa1 = *(const short8*)&ag[row * AGP + 32 + quad * 8];
        short8 ah0 = *(const short8*)(h1 + rbase + quad * 8);
        short8 ah1 = *(const short8*)(h1 + rbase + 32 + quad * 8);

        f32x4 acc = {bias, bias, bias, bias};
        acc = __builtin_amdgcn_mfma_f32_16x16x32_bf16(aa0, bwr[0], acc, 0, 0, 0);
        acc = __builtin_amdgcn_mfma_f32_16x16x32_bf16(aa1, bwr[1], acc, 0, 0, 0);
        acc = __builtin_amdgcn_mfma_f32_16x16x32_bf16(ah0, bwo[0], acc, 0, 0, 0);
        acc = __builtin_amdgcn_mfma_f32_16x16x32_bf16(ah1, bwo[1], acc, 0, 0, 0);

        float hv0 = fmaxf(acc[0], 0.0f), hv1 = fmaxf(acc[1], 0.0f);
        float hv2 = fmaxf(acc[2], 0.0f), hv3 = fmaxf(acc[3], 0.0f);

        int gLo = batch[m0], gHi = batch[m0 + 15];
        if (gLo == gHi) {
            float s = (hv0 + hv1) + (hv2 + hv3);
            s += __shfl_xor(s, 16, 64);
            s += __shfl_xor(s, 32, 64);
            if (quad == 0)
                atomicAdd(&add_pool[gLo * HIDDEN + n], s);
        } else {
            int m = m0 + quad * 4;
            atomicAdd(&add_pool[batch[m]     * HIDDEN + n], hv0);
            atomicAdd(&add_pool[batch[m + 1] * HIDDEN + n], hv1);
            atomicAdd(&add_pool[batch[m + 2] * HIDDEN + n], hv2);
            atomicAdd(&add_pool[batch[m + 3] * HIDDEN + n], hv3);
        }
        __syncthreads();   // protect ag before next tile's gather overwrites
    }

    // ---- completion protocol: last block runs the head ----
    if (tid == 0) {
        __threadfence();                         // order add_pool atomics before ctr
        int old = atomicAdd(done_ctr, 1);
        s_last = (old == (int)gridDim.x - 1) ? 1 : 0;
    }
    __syncthreads();
    if (!s_last) return;

    // head: one 64-lane wave per graph (4 waves -> 4 graphs per round)
    int gw = tid >> 6;    // wave id 0..3
    int tc = tid & 63;    // channel
    for (int g0 = gw; g0 < NUM_GRAPHS; g0 += 4) {
        int gs = lower_bound_i(batch, N_NODES, g0);
        int ge = lower_bound_i(batch, N_NODES, g0 + 1);
        float inv = 1.0f / fmaxf((float)(ge - gs), 1.0f);
        // coherent read of this graph's pooled row
        float a = atomicAdd(&add_pool[(size_t)g0 * HIDDEN + tc], 0.0f);
        float hid = b_h1[tc];
#pragma unroll 16
        for (int i = 0; i < HIDDEN; ++i) {
            float ai = __shfl(a, i, 64);
            hid += (ai * inv) * w_h1[i * HIDDEN + tc]      // mean-pool half
                 +  ai        * w_h1[(HIDDEN + i) * HIDDEN + tc]; // add-pool half
        }
        hid = fmaxf(hid, 0.0f);
        float res = hid * w_h2[tc];
        for (int off = 32; off > 0; off >>= 1)
            res += __shfl_down(res, off, 64);
        if (tc == 0) out[g0] = res + b_h2[0];
    }
}

extern "C" void kernel_launch(void* const* d_in, const int* in_sizes, int n_in,
                              void* d_out, int out_size, void* d_ws, size_t ws_size,
                              hipStream_t stream) {
    const float* x       = (const float*)d_in[0];
    const int*   ei      = (const int*)d_in[1];
    const int*   src     = ei;
    const int*   dst     = ei + N_EDGES;
    const int*   batch   = (const int*)d_in[2];
    const float* w_rel1  = (const float*)d_in[3];
    const float* b_rel1  = (const float*)d_in[4];
    const float* w_root1 = (const float*)d_in[5];
    const float* w_rel2  = (const float*)d_in[6];
    const float* b_rel2  = (const float*)d_in[7];
    const float* w_root2 = (const float*)d_in[8];
    const float* w_h1    = (const float*)d_in[9];
    const float* b_h1    = (const float*)d_in[10];
    const float* w_h2    = (const float*)d_in[11];
    const float* b_h2    = (const float*)d_in[12];
    float* out = (float*)d_out;

    int* base = (int*)d_ws;
    int*   gcnt     = base;                                   // CBLK*CB
    int*   btot     = gcnt + ((CBLK * CB + 3) & ~3);          // CB
    int*   bstart   = btot + ((CB + 3) & ~3);                 // CB+1
    int*   done_ctr = bstart + ((CB + 1 + 3) & ~3);           // 1 (pad 4)
    float* add_pool = (float*)(done_ctr + 4);                 // 128*64 f32
    int*   ptr      = (int*)(add_pool + NUM_GRAPHS * HIDDEN); // N+1
    int*   part     = ptr + ((N_NODES + 1 + 3) & ~3);         // E packed ints
    int*   esrc     = part + N_EDGES;                         // E
    unsigned short* h1   = (unsigned short*)(esrc + N_EDGES); // N*64 bf16
    unsigned char*  h1f8 = (unsigned char*)(h1 + (size_t)N_NODES * HIDDEN);   // N*64 fp8
    uint4*          xb   = (uint4*)(h1f8 + (size_t)N_NODES * HIDDEN);         // N*16B

    // ---- CSR build: 3 dispatches ----
    coarse_count<<<CBLK, 256, 0, stream>>>(dst, gcnt, x, xb, add_pool, ptr, done_ctr);
    block_scan<<<CB, CBLK, 0, stream>>>(gcnt, btot);
    partition_k<<<CBLK, 256, 0, stream>>>(src, dst, gcnt, btot, bstart, part);

    // ---- Fine sort + Layer 1 (fused; LDS-staged edge payloads) ----
    fine_gather1<<<CB, 256, 0, stream>>>(part, bstart, ptr, esrc, xb, x,
                                         w_rel1, b_rel1, w_root1, h1, h1f8);
    // ---- Layer 2 + head: gather + MFMA + pool + last-block head ----
    gather2_mlp2<<<G2BLKS, 256, 0, stream>>>((const unsigned*)h1f8, ptr, esrc, h1,
                                             w_rel2, b_rel2, w_root2, batch, add_pool,
                                             done_ctr, w_h1, b_h1, w_h2, b_h2, out);
}

// Round 11
// 193.620 us; speedup vs baseline: 2.5347x; 2.5347x over previous
//
#include <hip/hip_runtime.h>
#include <hip/hip_bf16.h>

#define N_NODES    100000
#define N_EDGES    1200000
#define NUM_GRAPHS 128
#define IN_DIM     5
#define HIDDEN     64
#define M_TILES    (N_NODES / 16)   // 6250 (exact; 6250*16 == N_NODES)
#define NI4        (N_EDGES / 4)    // 300000 int4 groups

#define CB    782                   // coarse buckets of 128 nodes: ceil(N/128)
#define CBLK  256                   // partition blocks
#define EPB   ((NI4 + CBLK - 1) / CBLK)   // 1172 int4-groups per block
#define STCAP 3072                  // LDS edge-payload capacity (avg 1534/bucket)
#define AGP   72                    // LDS gathered-tile row stride (halfwords)

typedef __attribute__((ext_vector_type(8))) short short8;   // 8 bf16 (4 VGPRs)
typedef __attribute__((ext_vector_type(4))) float f32x4;
typedef __attribute__((ext_vector_type(2))) float f32x2;

#if defined(__has_builtin)
#if __has_builtin(__builtin_amdgcn_cvt_pk_f32_fp8)
#define HAS_HWF8 1
#endif
#endif

// fp32 -> bf16 bits (RNE)
__device__ __forceinline__ unsigned short f2bs(float f) {
    union { float f; unsigned u; } v; v.f = f;
    return (unsigned short)((v.u + 0x7FFFu + ((v.u >> 16) & 1u)) >> 16);
}
// bf16 bits -> fp32
__device__ __forceinline__ float bs2f(unsigned short s) {
    union { unsigned u; float f; } v; v.u = ((unsigned)s) << 16;
    return v.f;
}
__device__ __forceinline__ float blo(unsigned p) { return bs2f((unsigned short)(p & 0xffff)); }
__device__ __forceinline__ float bhi(unsigned p) { return bs2f((unsigned short)(p >> 16)); }
__device__ __forceinline__ unsigned pack2(float a, float b) {
    return ((unsigned)f2bs(b) << 16) | (unsigned)f2bs(a);
}

// fp32 (>=0) -> fp8 e4m3 bits (OCP), RNE, denorm-exact (magic-multiply trick)
__device__ __forceinline__ unsigned char f2f8(float f) {
    union { float f; unsigned u; } v; v.f = f * 0x1p-120f;
    unsigned u = v.u + 0x7FFFFu + ((v.u >> 20) & 1u);
    return (unsigned char)(u >> 20);
}
// fp8 e4m3 bits -> fp32 (exact inverse)
__device__ __forceinline__ float f82f(unsigned b) {
    union { unsigned u; float f; } v; v.u = (b & 0x7Fu) << 20;
    return v.f * 0x1p120f;
}

// accumulate 4 fp8 bytes of r into a (HW decode when available; bit-identical)
__device__ __forceinline__ void acc8(float4& a, unsigned r) {
#ifdef HAS_HWF8
    f32x2 lo = __builtin_amdgcn_cvt_pk_f32_fp8((int)r, false);
    f32x2 hi = __builtin_amdgcn_cvt_pk_f32_fp8((int)r, true);
    a.x += lo[0]; a.y += lo[1]; a.z += hi[0]; a.w += hi[1];
#else
    a.x += f82f(r); a.y += f82f(r >> 8); a.z += f82f(r >> 16); a.w += f82f(r >> 24);
#endif
}

// ==================== CSR build: two-level counting sort ====================
// part entries are PACKED 4B: src (bits 0..16) | (dst & 127) << 17.
// Ledger: no grid.sync (r6: ~45us each); no per-block column-sum self-scan
// (r7: latency-bound, 65us); dispatch boundaries are cheap (~1-2us, r8);
// NEVER append cold epilogue code to a latency-critical kernel (r10: 8x).

// ---- Pass A: coarse histogram (dst>>7, LDS) + xb pack + misc init ----------
__global__ void coarse_count(const int* __restrict__ dst, int* __restrict__ gcnt,
                             const float* __restrict__ x, uint4* __restrict__ xb,
                             float* __restrict__ add_pool, int* __restrict__ ptr) {
    __shared__ int h[CB];
    int t = threadIdx.x, b = blockIdx.x;
    for (int i = t; i < CB; i += 256) h[i] = 0;
    __syncthreads();
    int i0 = b * EPB, i1 = min(i0 + EPB, NI4);
    for (int i = i0 + t; i < i1; i += 256) {
        int4 d = ((const int4*)dst)[i];
        atomicAdd(&h[d.x >> 7], 1);
        atomicAdd(&h[d.y >> 7], 1);
        atomicAdd(&h[d.z >> 7], 1);
        atomicAdd(&h[d.w >> 7], 1);
    }
    __syncthreads();
    for (int i = t; i < CB; i += 256) gcnt[b * CB + i] = h[i];

    // fold: pack x rows into 16B (5 bf16 + pad) for the layer-1 edge gather
    for (int n = b * 256 + t; n < N_NODES; n += CBLK * 256) {
        const float* xr = x + (size_t)n * IN_DIM;
        uint4 o;
        o.x = pack2(xr[0], xr[1]);
        o.y = pack2(xr[2], xr[3]);
        o.z = pack2(xr[4], 0.0f);
        o.w = 0u;
        xb[n] = o;
    }
    // fold: zero add_pool, terminate ptr
    if (b == 0) {
        for (int i = t; i < NUM_GRAPHS * HIDDEN; i += 256) add_pool[i] = 0.0f;
        if (t == 0) ptr[N_NODES] = N_EDGES;
    }
}

// ---- Pass B: per-bucket exclusive scan over the 256 partition blocks -------
__global__ void block_scan(int* __restrict__ gcnt, int* __restrict__ btot) {
    __shared__ int s[CBLK];
    int k = blockIdx.x, t = threadIdx.x;
    int v = gcnt[t * CB + k];
    s[t] = v;
    __syncthreads();
    for (int off = 1; off < CBLK; off <<= 1) {
        int u = (t >= off) ? s[t - off] : 0;
        __syncthreads();
        s[t] += u;
        __syncthreads();
    }
    gcnt[t * CB + k] = s[t] - v;
    if (t == CBLK - 1) btot[k] = s[t];
}

// ---- Pass C: partition; bstart recomputed locally from btot (cheap) --------
__global__ void partition_k(const int* __restrict__ src, const int* __restrict__ dst,
                            const int* __restrict__ gcnt, const int* __restrict__ btot,
                            int* __restrict__ bstart, int* __restrict__ part) {
    __shared__ int sb[CB];    // btot -> exclusive bucket starts
    __shared__ int base[CB];  // this block's write cursors base
    __shared__ int h[CB];     // scatter cursors
    int t = threadIdx.x, b = blockIdx.x;
    for (int i = t; i < CB; i += 256) sb[i] = btot[i];
    __syncthreads();
    if (t < 64) {
        int loc[13];                      // 64*13 = 832 >= CB
        int base_i = t * 13;
        int sum = 0;
#pragma unroll
        for (int j = 0; j < 13; ++j) {
            int idx = base_i + j;
            int c = (idx < CB) ? sb[idx] : 0;
            loc[j] = sum; sum += c;
        }
        int inc = sum;
#pragma unroll
        for (int off = 1; off < 64; off <<= 1) {
            int u = __shfl_up(inc, off, 64);
            if (t >= off) inc += u;
        }
        int excl = inc - sum;
#pragma unroll
        for (int j = 0; j < 13; ++j) {
            int idx = base_i + j;
            if (idx < CB) sb[idx] = excl + loc[j];
        }
    }
    __syncthreads();
    for (int i = t; i < CB; i += 256) {
        int bs = sb[i];
        base[i] = bs + gcnt[b * CB + i];
        h[i] = 0;
        if (b == 0) bstart[i] = bs;     // publish for fine_gather1
    }
    if (b == 0 && t == 0) bstart[CB] = N_EDGES;
    __syncthreads();
    int i0 = b * EPB, i1 = min(i0 + EPB, NI4);
    for (int i = i0 + t; i < i1; i += 256) {
        int4 s4 = ((const int4*)src)[i];
        int4 d4 = ((const int4*)dst)[i];
        int k, r;
        k = d4.x >> 7; r = atomicAdd(&h[k], 1); part[base[k] + r] = s4.x | ((d4.x & 127) << 17);
        k = d4.y >> 7; r = atomicAdd(&h[k], 1); part[base[k] + r] = s4.y | ((d4.y & 127) << 17);
        k = d4.z >> 7; r = atomicAdd(&h[k], 1); part[base[k] + r] = s4.z | ((d4.z & 127) << 17);
        k = d4.w >> 7; r = atomicAdd(&h[k], 1); part[base[k] + r] = s4.w | ((d4.w & 127) << 17);
    }
}

// ---- Pass D FUSED with Layer 1: fine sort + ptr + LDS-staged gather + MLP --
__global__ void fine_gather1(const int* __restrict__ part, const int* __restrict__ bstart,
                             int* __restrict__ ptr, int* __restrict__ esrc,
                             const uint4* __restrict__ xb,
                             const float* __restrict__ x,
                             const float* __restrict__ w_rel1,
                             const float* __restrict__ b_rel1,
                             const float* __restrict__ w_root1,
                             unsigned short* __restrict__ h1,
                             unsigned char* __restrict__ h1f8) {
    __shared__ int fh[128];       // counts -> exclusive offsets (bucket-local)
    __shared__ int fo[128];       // scan workspace
    __shared__ int fr[128];       // scatter cursors
    __shared__ uint4 stage[STCAP];// 48 KB edge payloads in slot order
    int k = blockIdx.x, t = threadIdx.x;
    int e0 = bstart[k], e1 = bstart[k + 1];
    int ne = e1 - e0;
    bool useLds = (ne <= STCAP);
    if (t < 128) { fh[t] = 0; fr[t] = 0; }
    __syncthreads();
    for (int e = e0 + t; e < e1; e += 256)
        atomicAdd(&fh[(part[e] >> 17) & 127], 1);
    __syncthreads();
    int v = (t < 128) ? fh[t] : 0;
    if (t < 128) fo[t] = v;
    __syncthreads();
    for (int off = 1; off < 128; off <<= 1) {
        int u = (t >= off && t < 128) ? fo[t - off] : 0;
        __syncthreads();
        if (t < 128) fo[t] += u;
        __syncthreads();
    }
    if (t < 128) {
        int excl = fo[t] - v;
        int n_t = (k << 7) + t;
        if (n_t < N_NODES) ptr[n_t] = e0 + excl;
        fh[t] = excl;
    }
    __syncthreads();
    for (int e = e0 + t; e < e1; e += 256) {
        int p = part[e];
        int d = (p >> 17) & 127;
        int s = p & 0x1FFFF;
        int r = atomicAdd(&fr[d], 1);
        int slot = fh[d] + r;
        esrc[e0 + slot] = s;
        if (useLds) stage[slot] = xb[s];
    }
    __syncthreads();

    int ql = t & 15;
    int g  = t >> 4;
    float wr[IN_DIM][4], wo[IN_DIM][4], bias[4];
#pragma unroll
    for (int j = 0; j < 4; ++j) {
        int ch = ql * 4 + j;
        bias[j] = b_rel1[ch];
#pragma unroll
        for (int kk = 0; kk < IN_DIM; ++kk) {
            wr[kk][j] = w_rel1[kk * HIDDEN + ch];
            wo[kk][j] = w_root1[kk * HIDDEN + ch];
        }
    }

    for (int nl = g; nl < 128; nl += 16) {
        int n = (k << 7) + nl;
        if (n >= N_NODES) break;
        int s0 = fh[nl];
        int s1 = (nl < 127) ? fh[nl + 1] : ne;
        float a[IN_DIM] = {0.f, 0.f, 0.f, 0.f, 0.f};
        if (useLds) {
            for (int i = s0 + ql; i < s1; i += 16) {
                uint4 p = stage[i];
                a[0] += blo(p.x); a[1] += bhi(p.x);
                a[2] += blo(p.y); a[3] += bhi(p.y);
                a[4] += blo(p.z);
            }
        } else {
            for (int i = s0 + ql; i < s1; i += 16) {
                uint4 p = xb[esrc[e0 + i]];
                a[0] += blo(p.x); a[1] += bhi(p.x);
                a[2] += blo(p.y); a[3] += bhi(p.y);
                a[4] += blo(p.z);
            }
        }
#pragma unroll
        for (int kk = 0; kk < IN_DIM; ++kk) {
            a[kk] += __shfl_xor(a[kk], 1, 64);
            a[kk] += __shfl_xor(a[kk], 2, 64);
            a[kk] += __shfl_xor(a[kk], 4, 64);
            a[kk] += __shfl_xor(a[kk], 8, 64);
        }
        float xr[IN_DIM];
#pragma unroll
        for (int kk = 0; kk < IN_DIM; ++kk) xr[kk] = x[(size_t)n * IN_DIM + kk];

        unsigned short hv[4];
        unsigned char  hf[4];
#pragma unroll
        for (int j = 0; j < 4; ++j) {
            float acc = bias[j];
#pragma unroll
            for (int kk = 0; kk < IN_DIM; ++kk)
                acc += a[kk] * wr[kk][j] + xr[kk] * wo[kk][j];
            float h = fmaxf(acc, 0.0f);
            hv[j] = f2bs(h);
            hf[j] = f2f8(h);
        }
        ushort4 v4; v4.x = hv[0]; v4.y = hv[1]; v4.z = hv[2]; v4.w = hv[3];
        *(ushort4*)(h1 + (size_t)n * HIDDEN + ql * 4) = v4;
        uchar4 c4; c4.x = hf[0]; c4.y = hf[1]; c4.z = hf[2]; c4.w = hf[3];
        *(uchar4*)(h1f8 + (size_t)n * HIDDEN + ql * 4) = c4;
    }
}

// ==================== Layer 2: gather + MFMA transform + pool, FUSED ========
// Per 16-node tile: 16 groups x 16 lanes gather all 16 fp8 rows in parallel
// (lane ql owns dword ql), pack bf16 into a padded LDS tile, then the 4 waves
// run the MFMA transform + add-pool on it. agg2 never touches global memory.
// 4-deep gather unroll: the gather chain is on the block-critical path here
// (gather -> syncthreads -> MFMA per tile), so halving chain depth pays.
__global__ void gather2_mlp2(const unsigned* __restrict__ rows,   // fp8 row = 16 dwords
                             const int* __restrict__ ptr,
                             const int* __restrict__ esrc,
                             const unsigned short* __restrict__ h1,
                             const float* __restrict__ w_rel2,
                             const float* __restrict__ b_rel2,
                             const float* __restrict__ w_root2,
                             const int* __restrict__ batch,
                             float* __restrict__ add_pool) {
    __shared__ unsigned short ag[16 * AGP];   // gathered tile, bf16, pad 72
    int tid  = threadIdx.x;
    int lane = tid & 63, wv = tid >> 6;
    int row  = lane & 15, quad = lane >> 4;
    int n    = wv * 16 + row;                 // this lane's output column
    int g    = tid >> 4, ql = tid & 15;       // gather roles

    short8 bwr[2], bwo[2];
#pragma unroll
    for (int s = 0; s < 2; ++s)
#pragma unroll
        for (int j = 0; j < 8; ++j) {
            int k = 32 * s + quad * 8 + j;
            bwr[s][j] = (short)f2bs(w_rel2[k * HIDDEN + n]);
            bwo[s][j] = (short)f2bs(w_root2[k * HIDDEN + n]);
        }
    float bias = b_rel2[n];

    for (int t = blockIdx.x; t < M_TILES; t += gridDim.x) {
        int m0 = t * 16;
        // ---- gather phase: group g gathers node m0+g (4 loads in flight) ---
        int nd = m0 + g;
        int start = ptr[nd], end = ptr[nd + 1];
        float4 a0 = {0.f, 0.f, 0.f, 0.f}, a1 = a0, a2 = a0, a3 = a0;
        int e = start;
        for (; e + 3 < end; e += 4) {
            int sA = esrc[e],     sB = esrc[e + 1];
            int sC = esrc[e + 2], sD = esrc[e + 3];
            unsigned r0 = rows[(size_t)sA * 16 + ql];
            unsigned r1 = rows[(size_t)sB * 16 + ql];
            unsigned r2 = rows[(size_t)sC * 16 + ql];
            unsigned r3 = rows[(size_t)sD * 16 + ql];
            acc8(a0, r0); acc8(a1, r1); acc8(a2, r2); acc8(a3, r3);
        }
        for (; e < end; ++e) {
            unsigned r0 = rows[(size_t)esrc[e] * 16 + ql];
            acc8(a0, r0);
        }
        a0.x += a1.x; a0.y += a1.y; a0.z += a1.z; a0.w += a1.w;
        a2.x += a3.x; a2.y += a3.y; a2.z += a3.z; a2.w += a3.w;
        a0.x += a2.x; a0.y += a2.y; a0.z += a2.z; a0.w += a2.w;
        uint2 pk;
        pk.x = pack2(a0.x, a0.y);
        pk.y = pack2(a0.z, a0.w);
        *(uint2*)&ag[g * AGP + ql * 4] = pk;
        __syncthreads();

        // ---- MFMA transform + pool (all 4 waves, same tile) ----
        size_t rbase = (size_t)(m0 + row) * HIDDEN;
        short8 aa0 = *(const short8*)&ag[row * AGP + quad * 8];
        short8 aa1 = *(const short8*)&ag[row * AGP + 32 + quad * 8];
        short8 ah0 = *(const short8*)(h1 + rbase + quad * 8);
        short8 ah1 = *(const short8*)(h1 + rbase + 32 + quad * 8);

        f32x4 acc = {bias, bias, bias, bias};
        acc = __builtin_amdgcn_mfma_f32_16x16x32_bf16(aa0, bwr[0], acc, 0, 0, 0);
        acc = __builtin_amdgcn_mfma_f32_16x16x32_bf16(aa1, bwr[1], acc, 0, 0, 0);
        acc = __builtin_amdgcn_mfma_f32_16x16x32_bf16(ah0, bwo[0], acc, 0, 0, 0);
        acc = __builtin_amdgcn_mfma_f32_16x16x32_bf16(ah1, bwo[1], acc, 0, 0, 0);

        float hv0 = fmaxf(acc[0], 0.0f), hv1 = fmaxf(acc[1], 0.0f);
        float hv2 = fmaxf(acc[2], 0.0f), hv3 = fmaxf(acc[3], 0.0f);

        int gLo = batch[m0], gHi = batch[m0 + 15];
        if (gLo == gHi) {
            float s = (hv0 + hv1) + (hv2 + hv3);
            s += __shfl_xor(s, 16, 64);
            s += __shfl_xor(s, 32, 64);
            if (quad == 0)
                atomicAdd(&add_pool[gLo * HIDDEN + n], s);
        } else {
            int m = m0 + quad * 4;
            atomicAdd(&add_pool[batch[m]     * HIDDEN + n], hv0);
            atomicAdd(&add_pool[batch[m + 1] * HIDDEN + n], hv1);
            atomicAdd(&add_pool[batch[m + 2] * HIDDEN + n], hv2);
            atomicAdd(&add_pool[batch[m + 3] * HIDDEN + n], hv3);
        }
        __syncthreads();   // protect ag before next tile's gather overwrites
    }
}

// ---- MLP head: one block (64 threads) per graph ----------------------------
__device__ __forceinline__ int lower_bound_i(const int* a, int n, int v) {
    int lo = 0, hi = n;
    while (lo < hi) { int mid = (lo + hi) >> 1; if (a[mid] < v) lo = mid + 1; else hi = mid; }
    return lo;
}

__global__ void head_mlp(const float* __restrict__ add_pool,
                         const int* __restrict__ batch,
                         const float* __restrict__ w_h1,
                         const float* __restrict__ b_h1,
                         const float* __restrict__ w_h2,
                         const float* __restrict__ b_h2,
                         float* __restrict__ out) {
    int g = blockIdx.x, t = threadIdx.x;

    __shared__ int s_cnt;
    if (t == 0) {
        int start = lower_bound_i(batch, N_NODES, g);
        int end   = lower_bound_i(batch, N_NODES, g + 1);
        s_cnt = end - start;
    }
    __syncthreads();
    float cnt = fmaxf((float)s_cnt, 1.0f);

    __shared__ float sg[2 * HIDDEN];
    float add = add_pool[(size_t)g * HIDDEN + t];
    sg[t]          = add / cnt;   // mean_pool
    sg[HIDDEN + t] = add;         // add_pool
    __syncthreads();

    float hid = b_h1[t];
#pragma unroll 16
    for (int i = 0; i < 2 * HIDDEN; ++i)
        hid += sg[i] * w_h1[i * HIDDEN + t];
    hid = fmaxf(hid, 0.0f);

    float res = hid * w_h2[t];
    for (int off = 32; off > 0; off >>= 1)
        res += __shfl_down(res, off, 64);
    if (t == 0) out[g] = res + b_h2[0];
}

extern "C" void kernel_launch(void* const* d_in, const int* in_sizes, int n_in,
                              void* d_out, int out_size, void* d_ws, size_t ws_size,
                              hipStream_t stream) {
    const float* x       = (const float*)d_in[0];
    const int*   ei      = (const int*)d_in[1];
    const int*   src     = ei;
    const int*   dst     = ei + N_EDGES;
    const int*   batch   = (const int*)d_in[2];
    const float* w_rel1  = (const float*)d_in[3];
    const float* b_rel1  = (const float*)d_in[4];
    const float* w_root1 = (const float*)d_in[5];
    const float* w_rel2  = (const float*)d_in[6];
    const float* b_rel2  = (const float*)d_in[7];
    const float* w_root2 = (const float*)d_in[8];
    const float* w_h1    = (const float*)d_in[9];
    const float* b_h1    = (const float*)d_in[10];
    const float* w_h2    = (const float*)d_in[11];
    const float* b_h2    = (const float*)d_in[12];
    float* out = (float*)d_out;

    int* base = (int*)d_ws;
    int*   gcnt     = base;                                   // CBLK*CB
    int*   btot     = gcnt + ((CBLK * CB + 3) & ~3);          // CB
    int*   bstart   = btot + ((CB + 3) & ~3);                 // CB+1
    float* add_pool = (float*)(bstart + ((CB + 1 + 3) & ~3)); // 128*64 f32
    int*   ptr      = (int*)(add_pool + NUM_GRAPHS * HIDDEN); // N+1
    int*   part     = ptr + ((N_NODES + 1 + 3) & ~3);         // E packed ints
    int*   esrc     = part + N_EDGES;                         // E
    unsigned short* h1   = (unsigned short*)(esrc + N_EDGES); // N*64 bf16
    unsigned char*  h1f8 = (unsigned char*)(h1 + (size_t)N_NODES * HIDDEN);   // N*64 fp8
    uint4*          xb   = (uint4*)(h1f8 + (size_t)N_NODES * HIDDEN);         // N*16B

    // ---- CSR build: 3 dispatches ----
    coarse_count<<<CBLK, 256, 0, stream>>>(dst, gcnt, x, xb, add_pool, ptr);
    block_scan<<<CB, CBLK, 0, stream>>>(gcnt, btot);
    partition_k<<<CBLK, 256, 0, stream>>>(src, dst, gcnt, btot, bstart, part);

    // ---- Fine sort + Layer 1 (fused; LDS-staged edge payloads) ----
    fine_gather1<<<CB, 256, 0, stream>>>(part, bstart, ptr, esrc, xb, x,
                                         w_rel1, b_rel1, w_root1, h1, h1f8);
    // ---- Layer 2: gather + MFMA transform + pool, all in one kernel ----
    gather2_mlp2<<<2048, 256, 0, stream>>>((const unsigned*)h1f8, ptr, esrc, h1,
                                           w_rel2, b_rel2, w_root2, batch, add_pool);
    // ---- Head ----
    head_mlp<<<NUM_GRAPHS, 64, 0, stream>>>(add_pool, batch, w_h1, b_h1, w_h2, b_h2, out);
}

// Round 12
// 192.182 us; speedup vs baseline: 2.5536x; 1.0075x over previous
//
#include <hip/hip_runtime.h>
#include <hip/hip_bf16.h>

#define N_NODES    100000
#define N_EDGES    1200000
#define NUM_GRAPHS 128
#define IN_DIM     5
#define HIDDEN     64
#define M_TILES    (N_NODES / 16)   // 6250 (exact; 6250*16 == N_NODES)
#define NI4        (N_EDGES / 4)    // 300000 int4 groups

#define CB    782                   // coarse buckets of 128 nodes: ceil(N/128)
#define CBLK  256                   // partition blocks
#define EPB   ((NI4 + CBLK - 1) / CBLK)   // 1172 int4-groups per block
#define STCAP 3072                  // LDS edge-payload capacity (avg 1534/bucket)

typedef __attribute__((ext_vector_type(8))) short short8;   // 8 bf16 (4 VGPRs)
typedef __attribute__((ext_vector_type(4))) float f32x4;
typedef __attribute__((ext_vector_type(2))) float f32x2;

#if defined(__has_builtin)
#if __has_builtin(__builtin_amdgcn_cvt_pk_f32_fp8)
#define HAS_HWF8 1
#endif
#endif

// fp32 -> bf16 bits (RNE)
__device__ __forceinline__ unsigned short f2bs(float f) {
    union { float f; unsigned u; } v; v.f = f;
    return (unsigned short)((v.u + 0x7FFFu + ((v.u >> 16) & 1u)) >> 16);
}
// bf16 bits -> fp32
__device__ __forceinline__ float bs2f(unsigned short s) {
    union { unsigned u; float f; } v; v.u = ((unsigned)s) << 16;
    return v.f;
}
__device__ __forceinline__ float blo(unsigned p) { return bs2f((unsigned short)(p & 0xffff)); }
__device__ __forceinline__ float bhi(unsigned p) { return bs2f((unsigned short)(p >> 16)); }
__device__ __forceinline__ unsigned pack2(float a, float b) {
    return ((unsigned)f2bs(b) << 16) | (unsigned)f2bs(a);
}

// fp32 (>=0) -> fp8 e4m3 bits (OCP), RNE, denorm-exact (magic-multiply trick)
__device__ __forceinline__ unsigned char f2f8(float f) {
    union { float f; unsigned u; } v; v.f = f * 0x1p-120f;
    unsigned u = v.u + 0x7FFFFu + ((v.u >> 20) & 1u);
    return (unsigned char)(u >> 20);
}
// fp8 e4m3 bits -> fp32 (exact inverse)
__device__ __forceinline__ float f82f(unsigned b) {
    union { unsigned u; float f; } v; v.u = (b & 0x7Fu) << 20;
    return v.f * 0x1p120f;
}

// accumulate 4 fp8 bytes of r into a (HW decode when available; bit-identical)
__device__ __forceinline__ void acc8(float4& a, unsigned r) {
#ifdef HAS_HWF8
    f32x2 lo = __builtin_amdgcn_cvt_pk_f32_fp8((int)r, false);
    f32x2 hi = __builtin_amdgcn_cvt_pk_f32_fp8((int)r, true);
    a.x += lo[0]; a.y += lo[1]; a.z += hi[0]; a.w += hi[1];
#else
    a.x += f82f(r); a.y += f82f(r >> 8); a.z += f82f(r >> 16); a.w += f82f(r >> 24);
#endif
}

// ==================== CSR build: two-level counting sort ====================
// part entries are PACKED 4B: src (bits 0..16) | (dst & 127) << 17.
// Ledger: no grid.sync (r6: ~45us each); no per-block column-sum self-scan
// (r7: latency-bound, 65us); dispatch boundaries are cheap (~1-2us, r8);
// NEVER append cold epilogue code to a latency-critical kernel (r10: 8x);
// barrier-synced gather/MFMA tile loop is convoy-bound (r11: warm-cache
// replay at identical duration).

// ---- Pass A: coarse histogram (dst>>7, LDS) + xb pack + misc init ----------
__global__ void coarse_count(const int* __restrict__ dst, int* __restrict__ gcnt,
                             const float* __restrict__ x, uint4* __restrict__ xb,
                             float* __restrict__ add_pool, int* __restrict__ ptr) {
    __shared__ int h[CB];
    int t = threadIdx.x, b = blockIdx.x;
    for (int i = t; i < CB; i += 256) h[i] = 0;
    __syncthreads();
    int i0 = b * EPB, i1 = min(i0 + EPB, NI4);
    for (int i = i0 + t; i < i1; i += 256) {
        int4 d = ((const int4*)dst)[i];
        atomicAdd(&h[d.x >> 7], 1);
        atomicAdd(&h[d.y >> 7], 1);
        atomicAdd(&h[d.z >> 7], 1);
        atomicAdd(&h[d.w >> 7], 1);
    }
    __syncthreads();
    for (int i = t; i < CB; i += 256) gcnt[b * CB + i] = h[i];

    // fold: pack x rows into 16B (5 bf16 + pad) for the layer-1 edge gather
    for (int n = b * 256 + t; n < N_NODES; n += CBLK * 256) {
        const float* xr = x + (size_t)n * IN_DIM;
        uint4 o;
        o.x = pack2(xr[0], xr[1]);
        o.y = pack2(xr[2], xr[3]);
        o.z = pack2(xr[4], 0.0f);
        o.w = 0u;
        xb[n] = o;
    }
    // fold: zero add_pool, terminate ptr
    if (b == 0) {
        for (int i = t; i < NUM_GRAPHS * HIDDEN; i += 256) add_pool[i] = 0.0f;
        if (t == 0) ptr[N_NODES] = N_EDGES;
    }
}

// ---- Pass B: per-bucket exclusive scan over the 256 partition blocks -------
__global__ void block_scan(int* __restrict__ gcnt, int* __restrict__ btot) {
    __shared__ int s[CBLK];
    int k = blockIdx.x, t = threadIdx.x;
    int v = gcnt[t * CB + k];
    s[t] = v;
    __syncthreads();
    for (int off = 1; off < CBLK; off <<= 1) {
        int u = (t >= off) ? s[t - off] : 0;
        __syncthreads();
        s[t] += u;
        __syncthreads();
    }
    gcnt[t * CB + k] = s[t] - v;
    if (t == CBLK - 1) btot[k] = s[t];
}

// ---- Pass C: partition; bstart recomputed locally from btot (cheap) --------
__global__ void partition_k(const int* __restrict__ src, const int* __restrict__ dst,
                            const int* __restrict__ gcnt, const int* __restrict__ btot,
                            int* __restrict__ bstart, int* __restrict__ part) {
    __shared__ int sb[CB];    // btot -> exclusive bucket starts
    __shared__ int base[CB];  // this block's write cursors base
    __shared__ int h[CB];     // scatter cursors
    int t = threadIdx.x, b = blockIdx.x;
    for (int i = t; i < CB; i += 256) sb[i] = btot[i];
    __syncthreads();
    if (t < 64) {
        int loc[13];                      // 64*13 = 832 >= CB
        int base_i = t * 13;
        int sum = 0;
#pragma unroll
        for (int j = 0; j < 13; ++j) {
            int idx = base_i + j;
            int c = (idx < CB) ? sb[idx] : 0;
            loc[j] = sum; sum += c;
        }
        int inc = sum;
#pragma unroll
        for (int off = 1; off < 64; off <<= 1) {
            int u = __shfl_up(inc, off, 64);
            if (t >= off) inc += u;
        }
        int excl = inc - sum;
#pragma unroll
        for (int j = 0; j < 13; ++j) {
            int idx = base_i + j;
            if (idx < CB) sb[idx] = excl + loc[j];
        }
    }
    __syncthreads();
    for (int i = t; i < CB; i += 256) {
        int bs = sb[i];
        base[i] = bs + gcnt[b * CB + i];
        h[i] = 0;
        if (b == 0) bstart[i] = bs;     // publish for fine_gather1
    }
    if (b == 0 && t == 0) bstart[CB] = N_EDGES;
    __syncthreads();
    int i0 = b * EPB, i1 = min(i0 + EPB, NI4);
    for (int i = i0 + t; i < i1; i += 256) {
        int4 s4 = ((const int4*)src)[i];
        int4 d4 = ((const int4*)dst)[i];
        int k, r;
        k = d4.x >> 7; r = atomicAdd(&h[k], 1); part[base[k] + r] = s4.x | ((d4.x & 127) << 17);
        k = d4.y >> 7; r = atomicAdd(&h[k], 1); part[base[k] + r] = s4.y | ((d4.y & 127) << 17);
        k = d4.z >> 7; r = atomicAdd(&h[k], 1); part[base[k] + r] = s4.z | ((d4.z & 127) << 17);
        k = d4.w >> 7; r = atomicAdd(&h[k], 1); part[base[k] + r] = s4.w | ((d4.w & 127) << 17);
    }
}

// ---- Pass D FUSED with Layer 1: fine sort + ptr + LDS-staged gather + MLP --
__global__ void fine_gather1(const int* __restrict__ part, const int* __restrict__ bstart,
                             int* __restrict__ ptr, int* __restrict__ esrc,
                             const uint4* __restrict__ xb,
                             const float* __restrict__ x,
                             const float* __restrict__ w_rel1,
                             const float* __restrict__ b_rel1,
                             const float* __restrict__ w_root1,
                             unsigned short* __restrict__ h1,
                             unsigned char* __restrict__ h1f8) {
    __shared__ int fh[128];       // counts -> exclusive offsets (bucket-local)
    __shared__ int fo[128];       // scan workspace
    __shared__ int fr[128];       // scatter cursors
    __shared__ uint4 stage[STCAP];// 48 KB edge payloads in slot order
    int k = blockIdx.x, t = threadIdx.x;
    int e0 = bstart[k], e1 = bstart[k + 1];
    int ne = e1 - e0;
    bool useLds = (ne <= STCAP);
    if (t < 128) { fh[t] = 0; fr[t] = 0; }
    __syncthreads();
    for (int e = e0 + t; e < e1; e += 256)
        atomicAdd(&fh[(part[e] >> 17) & 127], 1);
    __syncthreads();
    int v = (t < 128) ? fh[t] : 0;
    if (t < 128) fo[t] = v;
    __syncthreads();
    for (int off = 1; off < 128; off <<= 1) {
        int u = (t >= off && t < 128) ? fo[t - off] : 0;
        __syncthreads();
        if (t < 128) fo[t] += u;
        __syncthreads();
    }
    if (t < 128) {
        int excl = fo[t] - v;
        int n_t = (k << 7) + t;
        if (n_t < N_NODES) ptr[n_t] = e0 + excl;
        fh[t] = excl;
    }
    __syncthreads();
    for (int e = e0 + t; e < e1; e += 256) {
        int p = part[e];
        int d = (p >> 17) & 127;
        int s = p & 0x1FFFF;
        int r = atomicAdd(&fr[d], 1);
        int slot = fh[d] + r;
        esrc[e0 + slot] = s;
        if (useLds) stage[slot] = xb[s];
    }
    __syncthreads();

    int ql = t & 15;
    int g  = t >> 4;
    float wr[IN_DIM][4], wo[IN_DIM][4], bias[4];
#pragma unroll
    for (int j = 0; j < 4; ++j) {
        int ch = ql * 4 + j;
        bias[j] = b_rel1[ch];
#pragma unroll
        for (int kk = 0; kk < IN_DIM; ++kk) {
            wr[kk][j] = w_rel1[kk * HIDDEN + ch];
            wo[kk][j] = w_root1[kk * HIDDEN + ch];
        }
    }

    for (int nl = g; nl < 128; nl += 16) {
        int n = (k << 7) + nl;
        if (n >= N_NODES) break;
        int s0 = fh[nl];
        int s1 = (nl < 127) ? fh[nl + 1] : ne;
        float a[IN_DIM] = {0.f, 0.f, 0.f, 0.f, 0.f};
        if (useLds) {
            for (int i = s0 + ql; i < s1; i += 16) {
                uint4 p = stage[i];
                a[0] += blo(p.x); a[1] += bhi(p.x);
                a[2] += blo(p.y); a[3] += bhi(p.y);
                a[4] += blo(p.z);
            }
        } else {
            for (int i = s0 + ql; i < s1; i += 16) {
                uint4 p = xb[esrc[e0 + i]];
                a[0] += blo(p.x); a[1] += bhi(p.x);
                a[2] += blo(p.y); a[3] += bhi(p.y);
                a[4] += blo(p.z);
            }
        }
#pragma unroll
        for (int kk = 0; kk < IN_DIM; ++kk) {
            a[kk] += __shfl_xor(a[kk], 1, 64);
            a[kk] += __shfl_xor(a[kk], 2, 64);
            a[kk] += __shfl_xor(a[kk], 4, 64);
            a[kk] += __shfl_xor(a[kk], 8, 64);
        }
        float xr[IN_DIM];
#pragma unroll
        for (int kk = 0; kk < IN_DIM; ++kk) xr[kk] = x[(size_t)n * IN_DIM + kk];

        unsigned short hv[4];
        unsigned char  hf[4];
#pragma unroll
        for (int j = 0; j < 4; ++j) {
            float acc = bias[j];
#pragma unroll
            for (int kk = 0; kk < IN_DIM; ++kk)
                acc += a[kk] * wr[kk][j] + xr[kk] * wo[kk][j];
            float h = fmaxf(acc, 0.0f);
            hv[j] = f2bs(h);
            hf[j] = f2f8(h);
        }
        ushort4 v4; v4.x = hv[0]; v4.y = hv[1]; v4.z = hv[2]; v4.w = hv[3];
        *(ushort4*)(h1 + (size_t)n * HIDDEN + ql * 4) = v4;
        uchar4 c4; c4.x = hf[0]; c4.y = hf[1]; c4.z = hf[2]; c4.w = hf[3];
        *(uchar4*)(h1f8 + (size_t)n * HIDDEN + ql * 4) = c4;
    }
}

// ==================== Layer 2: wave-private gather + MFMA + pool ============
// Each WAVE owns a whole 16-node tile. Lane (quad q, r=lane&15) gathers the
// MFMA A-fragment DIRECTLY into registers: channels {q*8..q*8+7} (aa0) and
// {32+q*8..+7} (aa1) of node m0+r = fp8-row dwords {2q,2q+1} and {8+2q,9+2q}
// (8B-aligned uint2 loads). NO LDS tile, NO __syncthreads: waves free-run,
// MFMA of one wave overlaps gathers of siblings (fix for r11's convoy).
// Weights for all 4 output-column blocks live in registers (64 VGPR).
__global__ void gather2_mlp2(const unsigned* __restrict__ rows,   // fp8 row = 16 dwords
                             const int* __restrict__ ptr,
                             const int* __restrict__ esrc,
                             const unsigned short* __restrict__ h1,
                             const float* __restrict__ w_rel2,
                             const float* __restrict__ b_rel2,
                             const float* __restrict__ w_root2,
                             const int* __restrict__ batch,
                             float* __restrict__ add_pool) {
    int tid  = threadIdx.x;
    int lane = tid & 63, wv = tid >> 6;
    int r    = lane & 15, quad = lane >> 4;

    // weights for ALL 4 column blocks: bwr[cb][s][j] = W[32s+q*8+j][cb*16+r]
    short8 bwr[4][2], bwo[4][2];
    float bias[4];
#pragma unroll
    for (int cb = 0; cb < 4; ++cb) {
        int n = cb * 16 + r;
        bias[cb] = b_rel2[n];
#pragma unroll
        for (int s = 0; s < 2; ++s)
#pragma unroll
            for (int j = 0; j < 8; ++j) {
                int k = 32 * s + quad * 8 + j;
                bwr[cb][s][j] = (short)f2bs(w_rel2[k * HIDDEN + n]);
                bwo[cb][s][j] = (short)f2bs(w_root2[k * HIDDEN + n]);
            }
    }

    int gw = blockIdx.x * 4 + wv;        // global wave id
    int nw = gridDim.x * 4;
    for (int t = gw; t < M_TILES; t += nw) {
        int m0 = t * 16;
        // ---- fragment-direct gather: node m0+r, this quad's 4 dwords -------
        int start = ptr[m0 + r], end = ptr[m0 + r + 1];
        float4 ac0 = {0.f, 0.f, 0.f, 0.f}, ac1 = ac0, ac2 = ac0, ac3 = ac0;
        int e = start;
        for (; e + 1 < end; e += 2) {
            int s0 = esrc[e], s1 = esrc[e + 1];
            const unsigned* p0 = rows + (size_t)s0 * 16 + 2 * quad;
            const unsigned* p1 = rows + (size_t)s1 * 16 + 2 * quad;
            uint2 x0 = *(const uint2*)p0;
            uint2 y0 = *(const uint2*)(p0 + 8);
            uint2 x1 = *(const uint2*)p1;
            uint2 y1 = *(const uint2*)(p1 + 8);
            acc8(ac0, x0.x); acc8(ac1, x0.y); acc8(ac2, y0.x); acc8(ac3, y0.y);
            acc8(ac0, x1.x); acc8(ac1, x1.y); acc8(ac2, y1.x); acc8(ac3, y1.y);
        }
        if (e < end) {
            const unsigned* p0 = rows + (size_t)esrc[e] * 16 + 2 * quad;
            uint2 x0 = *(const uint2*)p0;
            uint2 y0 = *(const uint2*)(p0 + 8);
            acc8(ac0, x0.x); acc8(ac1, x0.y); acc8(ac2, y0.x); acc8(ac3, y0.y);
        }
        // build A fragments (bf16 RNE, same rounding point as before)
        short8 aa0, aa1;
        aa0[0] = (short)f2bs(ac0.x); aa0[1] = (short)f2bs(ac0.y);
        aa0[2] = (short)f2bs(ac0.z); aa0[3] = (short)f2bs(ac0.w);
        aa0[4] = (short)f2bs(ac1.x); aa0[5] = (short)f2bs(ac1.y);
        aa0[6] = (short)f2bs(ac1.z); aa0[7] = (short)f2bs(ac1.w);
        aa1[0] = (short)f2bs(ac2.x); aa1[1] = (short)f2bs(ac2.y);
        aa1[2] = (short)f2bs(ac2.z); aa1[3] = (short)f2bs(ac2.w);
        aa1[4] = (short)f2bs(ac3.x); aa1[5] = (short)f2bs(ac3.y);
        aa1[6] = (short)f2bs(ac3.z); aa1[7] = (short)f2bs(ac3.w);

        // root operand from h1 (same fragment role: row m0+r, ch quad*8+j)
        size_t rb = (size_t)(m0 + r) * HIDDEN;
        short8 ah0 = *(const short8*)(h1 + rb + quad * 8);
        short8 ah1 = *(const short8*)(h1 + rb + 32 + quad * 8);

        int gLo = batch[m0], gHi = batch[m0 + 15];
#pragma unroll
        for (int cb = 0; cb < 4; ++cb) {
            f32x4 acc = {bias[cb], bias[cb], bias[cb], bias[cb]};
            acc = __builtin_amdgcn_mfma_f32_16x16x32_bf16(aa0, bwr[cb][0], acc, 0, 0, 0);
            acc = __builtin_amdgcn_mfma_f32_16x16x32_bf16(aa1, bwr[cb][1], acc, 0, 0, 0);
            acc = __builtin_amdgcn_mfma_f32_16x16x32_bf16(ah0, bwo[cb][0], acc, 0, 0, 0);
            acc = __builtin_amdgcn_mfma_f32_16x16x32_bf16(ah1, bwo[cb][1], acc, 0, 0, 0);

            float hv0 = fmaxf(acc[0], 0.0f), hv1 = fmaxf(acc[1], 0.0f);
            float hv2 = fmaxf(acc[2], 0.0f), hv3 = fmaxf(acc[3], 0.0f);
            int n = cb * 16 + r;                // output channel (C col = lane&15)
            if (gLo == gHi) {
                float s = (hv0 + hv1) + (hv2 + hv3);
                s += __shfl_xor(s, 16, 64);
                s += __shfl_xor(s, 32, 64);
                if (quad == 0)
                    atomicAdd(&add_pool[gLo * HIDDEN + n], s);
            } else {
                int m = m0 + quad * 4;          // C row = node = quad*4 + j
                atomicAdd(&add_pool[batch[m]     * HIDDEN + n], hv0);
                atomicAdd(&add_pool[batch[m + 1] * HIDDEN + n], hv1);
                atomicAdd(&add_pool[batch[m + 2] * HIDDEN + n], hv2);
                atomicAdd(&add_pool[batch[m + 3] * HIDDEN + n], hv3);
            }
        }
    }
}

// ---- MLP head: one block (64 threads) per graph ----------------------------
__device__ __forceinline__ int lower_bound_i(const int* a, int n, int v) {
    int lo = 0, hi = n;
    while (lo < hi) { int mid = (lo + hi) >> 1; if (a[mid] < v) lo = mid + 1; else hi = mid; }
    return lo;
}

__global__ void head_mlp(const float* __restrict__ add_pool,
                         const int* __restrict__ batch,
                         const float* __restrict__ w_h1,
                         const float* __restrict__ b_h1,
                         const float* __restrict__ w_h2,
                         const float* __restrict__ b_h2,
                         float* __restrict__ out) {
    int g = blockIdx.x, t = threadIdx.x;

    __shared__ int s_cnt;
    if (t == 0) {
        int start = lower_bound_i(batch, N_NODES, g);
        int end   = lower_bound_i(batch, N_NODES, g + 1);
        s_cnt = end - start;
    }
    __syncthreads();
    float cnt = fmaxf((float)s_cnt, 1.0f);

    __shared__ float sg[2 * HIDDEN];
    float add = add_pool[(size_t)g * HIDDEN + t];
    sg[t]          = add / cnt;   // mean_pool
    sg[HIDDEN + t] = add;         // add_pool
    __syncthreads();

    float hid = b_h1[t];
#pragma unroll 16
    for (int i = 0; i < 2 * HIDDEN; ++i)
        hid += sg[i] * w_h1[i * HIDDEN + t];
    hid = fmaxf(hid, 0.0f);

    float res = hid * w_h2[t];
    for (int off = 32; off > 0; off >>= 1)
        res += __shfl_down(res, off, 64);
    if (t == 0) out[g] = res + b_h2[0];
}

extern "C" void kernel_launch(void* const* d_in, const int* in_sizes, int n_in,
                              void* d_out, int out_size, void* d_ws, size_t ws_size,
                              hipStream_t stream) {
    const float* x       = (const float*)d_in[0];
    const int*   ei      = (const int*)d_in[1];
    const int*   src     = ei;
    const int*   dst     = ei + N_EDGES;
    const int*   batch   = (const int*)d_in[2];
    const float* w_rel1  = (const float*)d_in[3];
    const float* b_rel1  = (const float*)d_in[4];
    const float* w_root1 = (const float*)d_in[5];
    const float* w_rel2  = (const float*)d_in[6];
    const float* b_rel2  = (const float*)d_in[7];
    const float* w_root2 = (const float*)d_in[8];
    const float* w_h1    = (const float*)d_in[9];
    const float* b_h1    = (const float*)d_in[10];
    const float* w_h2    = (const float*)d_in[11];
    const float* b_h2    = (const float*)d_in[12];
    float* out = (float*)d_out;

    int* base = (int*)d_ws;
    int*   gcnt     = base;                                   // CBLK*CB
    int*   btot     = gcnt + ((CBLK * CB + 3) & ~3);          // CB
    int*   bstart   = btot + ((CB + 3) & ~3);                 // CB+1
    float* add_pool = (float*)(bstart + ((CB + 1 + 3) & ~3)); // 128*64 f32
    int*   ptr      = (int*)(add_pool + NUM_GRAPHS * HIDDEN); // N+1
    int*   part     = ptr + ((N_NODES + 1 + 3) & ~3);         // E packed ints
    int*   esrc     = part + N_EDGES;                         // E
    unsigned short* h1   = (unsigned short*)(esrc + N_EDGES); // N*64 bf16
    unsigned char*  h1f8 = (unsigned char*)(h1 + (size_t)N_NODES * HIDDEN);   // N*64 fp8
    uint4*          xb   = (uint4*)(h1f8 + (size_t)N_NODES * HIDDEN);         // N*16B

    // ---- CSR build: 3 dispatches ----
    coarse_count<<<CBLK, 256, 0, stream>>>(dst, gcnt, x, xb, add_pool, ptr);
    block_scan<<<CB, CBLK, 0, stream>>>(gcnt, btot);
    partition_k<<<CBLK, 256, 0, stream>>>(src, dst, gcnt, btot, bstart, part);

    // ---- Fine sort + Layer 1 (fused; LDS-staged edge payloads) ----
    fine_gather1<<<CB, 256, 0, stream>>>(part, bstart, ptr, esrc, xb, x,
                                         w_rel1, b_rel1, w_root1, h1, h1f8);
    // ---- Layer 2: wave-private gather + MFMA + pool (barrier-free) ----
    gather2_mlp2<<<2048, 256, 0, stream>>>((const unsigned*)h1f8, ptr, esrc, h1,
                                           w_rel2, b_rel2, w_root2, batch, add_pool);
    // ---- Head ----
    head_mlp<<<NUM_GRAPHS, 64, 0, stream>>>(add_pool, batch, w_h1, b_h1, w_h2, b_h2, out);
}